// Round 6
// baseline (644.512 us; speedup 1.0000x reference)
//
#include <hip/hip_runtime.h>
#include <hip/hip_bf16.h>
#include <stdint.h>

// Problem constants
#define Bb 2
#define Ss 2048
#define Hh 2048
#define NHh 16
#define HDd 128
#define Pp 2048
#define Mm 4096   // B*S

typedef __bf16 bf16x8 __attribute__((ext_vector_type(8)));
typedef float f32x4 __attribute__((ext_vector_type(4)));
typedef float f32x16 __attribute__((ext_vector_type(16)));
typedef __hip_bfloat16 bf16_t;

static __device__ __forceinline__ bf16_t f2b(float f) { return __float2bfloat16(f); }
static __device__ __forceinline__ float b2f(bf16_t b) { return __bfloat162float(b); }

// ---------------- merged weight pack kernel ----------------
// regions: [0,4M) Wv->wv_bf ; [4M,12M) Wqk->wqk_bf ; [12M,16M) Wo->wo_bf ;
//          [16M,20M) conv1 pack ; [20M,24M) conv2 pack
__global__ void k_pack_weights(const float* __restrict__ Wv, const float* __restrict__ Wqk,
                               const float* __restrict__ Wo, const float* __restrict__ c1w,
                               const float* __restrict__ c2w, bf16_t* __restrict__ wv_bf,
                               bf16_t* __restrict__ wqk_bf, bf16_t* __restrict__ wo_bf,
                               bf16_t* __restrict__ w1cat, bf16_t* __restrict__ w2cat) {
  const int M4 = 4 * 1024 * 1024;
  int stride = gridDim.x * blockDim.x;
  for (int i = blockIdx.x * blockDim.x + threadIdx.x; i < 6 * M4; i += stride) {
    if (i < M4) {
      wv_bf[i] = f2b(Wv[i]);
    } else if (i < 3 * M4) {
      int j = i - M4;
      wqk_bf[j] = f2b(Wqk[j]);
    } else if (i < 4 * M4) {
      int j = i - 3 * M4;
      wo_bf[j] = f2b(Wo[j]);
    } else if (i < 5 * M4) {
      int j = i - 4 * M4;
      int o = j >> 12, hp = j & 4095;
      int t = hp >> 11, h = hp & 2047;
      w1cat[j] = f2b(c1w[((size_t)o * 2048 + h) * 2 + t]);
    } else {
      int j = i - 5 * M4;
      int o = j >> 11, cp = j & 2047;
      int t = cp >> 10, c = cp & 1023;
      w2cat[j] = f2b(c2w[((size_t)o * 1024 + c) * 2 + t]);
    }
  }
}

// x fp32 (B,S,H) -> xcat bf16 (4096,4096) = [x_shift | x]
__global__ void k_pack_x(const float* __restrict__ x, const float* __restrict__ lf1,
                         bf16_t* __restrict__ xcat) {
  int stride = gridDim.x * blockDim.x;
  for (int i = blockIdx.x * blockDim.x + threadIdx.x; i < Mm * Hh; i += stride) {
    int m = i >> 11, h = i & 2047;
    int b = m >> 11, s = m & 2047;
    float xv = x[i];
    xcat[(size_t)m * 4096 + 2048 + h] = f2b(xv);
    float xs = (s == 0) ? lf1[b * 2048 + h] : x[i - 2048];
    xcat[(size_t)m * 4096 + h] = f2b(xs);
  }
}

// y1cat left-half rows s==0 come from lf2 cache
__global__ void k_lf2fill(const float* __restrict__ lf2, bf16_t* __restrict__ y1cat) {
  int i = blockIdx.x * 256 + threadIdx.x;
  if (i >= 2048) return;
  int b = i >> 10, c = i & 1023;
  y1cat[(size_t)(b * 2048) * 2048 + c] = f2b(lf2[b * 1024 + c]);
}

// lf_out = rmsnorm(y2 + x, ln_w)  -> bf16 (4096,2048)
__global__ __launch_bounds__(256) void k_rmsnorm(const float* __restrict__ y2,
                                                 const float* __restrict__ x,
                                                 const float* __restrict__ w,
                                                 bf16_t* __restrict__ out) {
  int m = blockIdx.x;
  const float* yr = y2 + (size_t)m * 2048;
  const float* xr = x + (size_t)m * 2048;
  int tid = threadIdx.x;
  float t[8];
  float ss = 0.0f;
#pragma unroll
  for (int j = 0; j < 8; ++j) {
    int idx = tid + j * 256;
    float v = yr[idx] + xr[idx];
    t[j] = v;
    ss += v * v;
  }
#pragma unroll
  for (int o = 32; o >= 1; o >>= 1) ss += __shfl_xor(ss, o, 64);
  __shared__ float red[4];
  if ((tid & 63) == 0) red[tid >> 6] = ss;
  __syncthreads();
  float tot = red[0] + red[1] + red[2] + red[3];
  float rs = rsqrtf(tot * (1.0f / 2048.0f) + 1e-6f);
#pragma unroll
  for (int j = 0; j < 8; ++j) {
    int idx = tid + j * 256;
    out[(size_t)m * 2048 + idx] = f2b(t[j] * w[idx] * rs);
  }
}

// tails: lf1_new = x[:, S-1, :] (fp32), lf2_new = y1[:, S-1, :] (from y1cat bf16)
__global__ void k_tails(const float* __restrict__ x, const bf16_t* __restrict__ y1cat,
                        float* __restrict__ out) {
  int i = blockIdx.x * 256 + threadIdx.x;
  if (i >= 4096 + 2048) return;
  const size_t off = (size_t)Mm * Hh;  // 8388608
  if (i < 4096) {
    int b = i >> 11, h = i & 2047;
    out[off + i] = x[((size_t)b * 2048 + 2047) * 2048 + h];
  } else {
    int j = i - 4096;
    int b = j >> 10, c = j & 1023;
    out[off + 4096 + j] = b2f(y1cat[((size_t)b * 2048 + 2047) * 2048 + 1024 + c]);
  }
}

// ---------------- GEMM: C = A(M,K; lda) @ W(N,K)^T with fused epilogues ----------------
// LDS: single arena; epilogue transpose tiles OVERLAY the staging buffers (post-loop, barriered)
#define EPI_F32 0
#define EPI_Y1CAT 1
#define EPI_ROPE 2
#define EPI_VT 3

template <int EPI, int HAS_BIAS>
__global__ __launch_bounds__(256) void gemm_epi(const bf16_t* __restrict__ A,
                                                const bf16_t* __restrict__ Bw,
                                                void* __restrict__ C1, void* __restrict__ C2,
                                                const float* __restrict__ bias,
                                                const int* __restrict__ posp,
                                                const float* __restrict__ freqs,
                                                int M, int N, int K, int lda) {
  constexpr int SMEM_BYTES = (EPI == EPI_ROPE || EPI == EPI_VT) ? 34816 : 32768;
  __shared__ __align__(16) char smem[SMEM_BYTES];
  bf16_t* lA = (bf16_t*)smem;
  bf16_t* lB = (bf16_t*)(smem + 16384);

  const int tid = threadIdx.x;
  const int lane = tid & 63;
  const int row0 = blockIdx.x * 128;
  const int col0 = blockIdx.y * 128;
  const int wr = ((tid >> 6) >> 1) * 64;
  const int wc = ((tid >> 6) & 1) * 64;
  const int lr = lane & 15;
  const int lg = lane >> 4;

  f32x4 acc[4][4];
#pragma unroll
  for (int i = 0; i < 4; ++i)
#pragma unroll
    for (int j = 0; j < 4; ++j) acc[i][j] = f32x4{0.f, 0.f, 0.f, 0.f};

  for (int k0 = 0; k0 < K; k0 += 64) {
    __syncthreads();
#pragma unroll
    for (int is = 0; is < 4; ++is) {
      const int e = is * 2048 + tid * 8;
      const int r = e >> 6, c = e & 63;
      __builtin_amdgcn_global_load_lds(
          (const __attribute__((address_space(1))) void*)(A + (size_t)(row0 + r) * lda + (k0 + c)),
          (__attribute__((address_space(3))) void*)(&lA[e]), 16, 0, 0);
      __builtin_amdgcn_global_load_lds(
          (const __attribute__((address_space(1))) void*)(Bw + (size_t)(col0 + r) * K + (k0 + c)),
          (__attribute__((address_space(3))) void*)(&lB[e]), 16, 0, 0);
    }
    __syncthreads();
#pragma unroll
    for (int ks = 0; ks < 2; ++ks) {
      bf16x8 af[4], bfg[4];
#pragma unroll
      for (int mi = 0; mi < 4; ++mi)
        af[mi] = *reinterpret_cast<const bf16x8*>(&lA[(wr + mi * 16 + lr) * 64 + ks * 32 + lg * 8]);
#pragma unroll
      for (int ni = 0; ni < 4; ++ni)
        bfg[ni] = *reinterpret_cast<const bf16x8*>(&lB[(wc + ni * 16 + lr) * 64 + ks * 32 + lg * 8]);
#pragma unroll
      for (int mi = 0; mi < 4; ++mi)
#pragma unroll
        for (int ni = 0; ni < 4; ++ni)
          acc[mi][ni] = __builtin_amdgcn_mfma_f32_16x16x32_bf16(af[mi], bfg[ni], acc[mi][ni], 0, 0, 0);
    }
  }

  // ---- epilogues. Fragment (mi,ni,r): local row rl=wr+mi*16+lg*4+r, col cl=wc+ni*16+lr ----
  if constexpr (EPI == EPI_F32) {
#pragma unroll
    for (int mi = 0; mi < 4; ++mi)
#pragma unroll
      for (int ni = 0; ni < 4; ++ni) {
        const int cc = col0 + wc + ni * 16 + lr;
        float bv = HAS_BIAS ? bias[cc] : 0.0f;
#pragma unroll
        for (int r = 0; r < 4; ++r) {
          const int rr = row0 + wr + mi * 16 + lg * 4 + r;
          ((float*)C1)[(size_t)rr * N + cc] = acc[mi][ni][r] + bv;
        }
      }
  } else if constexpr (EPI == EPI_Y1CAT) {
    bf16_t* y1cat = (bf16_t*)C1;
#pragma unroll
    for (int mi = 0; mi < 4; ++mi)
#pragma unroll
      for (int ni = 0; ni < 4; ++ni) {
        const int cc = col0 + wc + ni * 16 + lr;  // 0..1023
        float bv = HAS_BIAS ? bias[cc] : 0.0f;
#pragma unroll
        for (int r = 0; r < 4; ++r) {
          const int rr = row0 + wr + mi * 16 + lg * 4 + r;
          bf16_t v = f2b(acc[mi][ni][r] + bv);
          y1cat[(size_t)rr * 2048 + 1024 + cc] = v;
          if ((rr & 2047) != 2047) y1cat[(size_t)(rr + 1) * 2048 + cc] = v;
        }
      }
  } else if constexpr (EPI == EPI_ROPE) {
    // col-block 128 = (head h, q|k half). Tile overlays staging LDS after barrier.
    __syncthreads();  // all waves done reading lA/lB
    bf16_t(*tile)[136] = (bf16_t(*)[136])smem;
#pragma unroll
    for (int mi = 0; mi < 4; ++mi)
#pragma unroll
      for (int ni = 0; ni < 4; ++ni) {
        const int cl = wc + ni * 16 + lr;
#pragma unroll
        for (int r = 0; r < 4; ++r) {
          const int rl = wr + mi * 16 + lg * 4 + r;
          tile[rl][cl] = f2b(acc[mi][ni][r]);
        }
      }
    __syncthreads();
    const int r = tid >> 1, half = tid & 1;
    const int m = row0 + r;
    const int s = m & 2047, bb = m >> 11;
    const int cb = col0 >> 7, h = cb >> 1, isk = cb & 1;
    const int pos = posp[m];
    const float* fr = freqs + (size_t)pos * HDd;
    const float qs = isk ? 1.0f : 0.08838834764831845f;
    bf16_t* dst = (bf16_t*)(isk ? C2 : C1) + ((size_t)(bb * NHh + h) * Ss + s) * HDd + half * 64;
#pragma unroll
    for (int j = 0; j < 8; ++j) {
      bf16x8 lo = *reinterpret_cast<const bf16x8*>(&tile[r][j * 8]);
      bf16x8 hv = *reinterpret_cast<const bf16x8*>(&tile[r][64 + j * 8]);
      bf16x8 ov;
#pragma unroll
      for (int e = 0; e < 8; ++e) {
        float f = fr[j * 8 + e];
        float sn, cs;
        __sincosf(f, &sn, &cs);
        float v0 = b2f((bf16_t)lo[e]), v1 = b2f((bf16_t)hv[e]);
        float o = half ? (v1 * cs + v0 * sn) : (v0 * cs - v1 * sn);
        ov[e] = (__bf16)f2b(o * qs);
      }
      *reinterpret_cast<bf16x8*>(dst + j * 8) = ov;
    }
  } else if constexpr (EPI == EPI_VT) {
    // col-block 128 = head h's d range. Transposed tile overlays staging LDS.
    __syncthreads();  // all waves done reading lA/lB
    bf16_t(*ttile)[136] = (bf16_t(*)[136])smem;
#pragma unroll
    for (int mi = 0; mi < 4; ++mi)
#pragma unroll
      for (int ni = 0; ni < 4; ++ni) {
        const int cl = wc + ni * 16 + lr;
#pragma unroll
        for (int r = 0; r < 4; ++r) {
          const int rl = wr + mi * 16 + lg * 4 + r;
          ttile[cl][rl] = f2b(acc[mi][ni][r]);
        }
      }
    __syncthreads();
    const int d = tid >> 1, sc = tid & 1;
    const int bb = row0 >> 11, s0 = row0 & 2047, h = col0 >> 7;
    bf16_t* dst = (bf16_t*)C1 + ((size_t)(bb * NHh + h) * HDd + d) * Ss + s0 + sc * 64;
#pragma unroll
    for (int j = 0; j < 8; ++j)
      *reinterpret_cast<bf16x8*>(dst + j * 8) =
          *reinterpret_cast<const bf16x8*>(&ttile[d][sc * 64 + j * 8]);
  }
}

// ---------------- flash attention v3 ----------------
// grid (32, 16). Balanced y-remap: y<8 -> q-tile 15-y (heavy first), y>=8 -> y-8.
// T14: prefetch next K/V tile into regs, ds_write after barrier. T5: setprio around MFMA.
__global__ __launch_bounds__(256) void k_attn3(const bf16_t* __restrict__ qa,
                                               const bf16_t* __restrict__ ka,
                                               const bf16_t* __restrict__ vt,
                                               bf16_t* __restrict__ attn_out) {
  __shared__ bf16_t kbuf[64 * 128];   // K tile [key][d], row 256B, swizzled
  __shared__ bf16_t vbuf[128 * 64];   // V^T tile [d][key], row 128B, swizzled
  __shared__ bf16_t pbuf[4][32 * 64]; // per-wave P [q][key], row 128B, swizzled

  const int tid = threadIdx.x;
  const int wave = tid >> 6, lane = tid & 63;
  const int l31 = lane & 31, hi = lane >> 5;
  const int bh = blockIdx.x;
  const int yy = blockIdx.y;
  const int jq = (yy < 8) ? (15 - yy) : (yy - 8);
  const int q0b = jq * 128;
  const int q0w = q0b + wave * 32;
  const int b = bh >> 4, h = bh & 15;

  const bf16_t* Q = qa + (size_t)bh * Ss * HDd;
  const bf16_t* K = ka + (size_t)bh * Ss * HDd;
  const bf16_t* V = vt + (size_t)bh * HDd * Ss;
  char* pw = (char*)&pbuf[wave][0];

  bf16x8 qf[8];
#pragma unroll
  for (int dc = 0; dc < 8; ++dc)
    qf[dc] = *reinterpret_cast<const bf16x8*>(&Q[(size_t)(q0w + l31) * HDd + dc * 16 + hi * 8]);

  f32x16 o[4];
#pragma unroll
  for (int db = 0; db < 4; ++db)
#pragma unroll
    for (int i = 0; i < 16; ++i) o[db][i] = 0.f;
  float mrun = -3e38f, lrun = 0.f;
  const int qrow = q0w + l31;

  const int nkt = q0b / 64 + 2;
  bf16x8 pk[4], pv[4];
  auto loadt = [&](int kt) {
    const int k0l = kt * 64;
#pragma unroll
    for (int i = 0; i < 4; ++i) {
      pk[i] = *reinterpret_cast<const bf16x8*>(
          &K[(size_t)(k0l + (tid >> 2)) * HDd + ((tid & 3) + 4 * i) * 8]);
      pv[i] = *reinterpret_cast<const bf16x8*>(
          &V[(size_t)(tid >> 1) * Ss + k0l + ((tid & 1) * 4 + i) * 8]);
    }
  };
  loadt(0);

  for (int kt = 0; kt < nkt; ++kt) {
    const int k0 = kt * 64;
    __syncthreads();  // prior tile's LDS reads complete
    {
      const int kr = tid >> 2, vr = tid >> 1;
#pragma unroll
      for (int i = 0; i < 4; ++i) {
        const int ku = (tid & 3) + 4 * i;
        *reinterpret_cast<bf16x8*>((char*)kbuf + kr * 256 + ((ku * 16) ^ ((kr & 7) << 4))) = pk[i];
        const int vu = (tid & 1) * 4 + i;
        *reinterpret_cast<bf16x8*>((char*)vbuf + vr * 128 + ((vu * 16) ^ ((vr & 7) << 4))) = pv[i];
      }
    }
    __syncthreads();
    if (kt + 1 < nkt) loadt(kt + 1);  // overlap next-tile loads with compute (T14)
    if (k0 > q0w + 31) continue;      // tile above this wave's causal range

    // ---- QK^T: A=K rows(key), B=Q cols(q) ----
    f32x16 s0, s1;
#pragma unroll
    for (int i = 0; i < 16; ++i) { s0[i] = 0.f; s1[i] = 0.f; }
    __builtin_amdgcn_s_setprio(1);
#pragma unroll
    for (int dc = 0; dc < 8; ++dc) {
      const int off = (dc * 32 + hi * 16) ^ ((l31 & 7) << 4);
      bf16x8 kf0 = *reinterpret_cast<const bf16x8*>((const char*)kbuf + l31 * 256 + off);
      bf16x8 kf1 = *reinterpret_cast<const bf16x8*>((const char*)kbuf + (32 + l31) * 256 + off);
      s0 = __builtin_amdgcn_mfma_f32_32x32x16_bf16(kf0, qf[dc], s0, 0, 0, 0);
      s1 = __builtin_amdgcn_mfma_f32_32x32x16_bf16(kf1, qf[dc], s1, 0, 0, 0);
    }
    __builtin_amdgcn_s_setprio(0);
    // ---- mask ----
    if (k0 + 63 > q0w) {
#pragma unroll
      for (int reg = 0; reg < 16; ++reg) {
        const int key = k0 + (reg & 3) + 8 * (reg >> 2) + 4 * hi;
        if (key > qrow) s0[reg] = -1e30f;
        if (key + 32 > qrow) s1[reg] = -1e30f;
      }
    }
    // ---- online softmax (lane-local; halves via shfl_xor 32) ----
    float pm = fmaxf(s0[0], s1[0]);
#pragma unroll
    for (int reg = 1; reg < 16; ++reg) pm = fmaxf(pm, fmaxf(s0[reg], s1[reg]));
    pm = fmaxf(pm, __shfl_xor(pm, 32, 64));
    if (!__all(pm - mrun <= 8.0f)) {  // defer-max (T13)
      const float mnew = fmaxf(mrun, pm);
      const float alpha = __expf(mrun - mnew);
      lrun *= alpha;
#pragma unroll
      for (int reg = 0; reg < 16; ++reg) {
        const int r = (reg & 3) + 8 * (reg >> 2) + 4 * hi;
        const float ar = __shfl(alpha, r, 64);
        o[0][reg] *= ar; o[1][reg] *= ar; o[2][reg] *= ar; o[3][reg] *= ar;
      }
      mrun = mnew;
    }
    float psum = 0.f;
#pragma unroll
    for (int reg = 0; reg < 16; ++reg) {
      s0[reg] = __expf(s0[reg] - mrun); psum += s0[reg];
      s1[reg] = __expf(s1[reg] - mrun); psum += s1[reg];
    }
    psum += __shfl_xor(psum, 32, 64);
    lrun += psum;
    // ---- P -> bf16 -> per-wave swizzled LDS: P[q=l31][key] ----
#pragma unroll
    for (int g = 0; g < 4; ++g) {
      uint32_t w0, w1, w2, w3;
      asm("v_cvt_pk_bf16_f32 %0, %1, %2" : "=v"(w0) : "v"(s0[4 * g]), "v"(s0[4 * g + 1]));
      asm("v_cvt_pk_bf16_f32 %0, %1, %2" : "=v"(w1) : "v"(s0[4 * g + 2]), "v"(s0[4 * g + 3]));
      asm("v_cvt_pk_bf16_f32 %0, %1, %2" : "=v"(w2) : "v"(s1[4 * g]), "v"(s1[4 * g + 1]));
      asm("v_cvt_pk_bf16_f32 %0, %1, %2" : "=v"(w3) : "v"(s1[4 * g + 2]), "v"(s1[4 * g + 3]));
      const int key0 = 8 * g + 4 * hi;
      const int sw = (l31 & 7) << 4;
      *reinterpret_cast<uint2*>(pw + l31 * 128 + ((key0 * 2) ^ sw)) = uint2{w0, w1};
      *reinterpret_cast<uint2*>(pw + l31 * 128 + (((key0 + 32) * 2) ^ sw)) = uint2{w2, w3};
    }
    // ---- PV ----
    __builtin_amdgcn_s_setprio(1);
#pragma unroll
    for (int kc = 0; kc < 4; ++kc) {
      bf16x8 pa = *reinterpret_cast<const bf16x8*>(
          pw + l31 * 128 + ((kc * 32 + hi * 16) ^ ((l31 & 7) << 4)));
#pragma unroll
      for (int db = 0; db < 4; ++db) {
        const int d = db * 32 + l31;
        bf16x8 vf = *reinterpret_cast<const bf16x8*>(
            (const char*)vbuf + d * 128 + ((kc * 32 + hi * 16) ^ ((d & 7) << 4)));
        o[db] = __builtin_amdgcn_mfma_f32_32x32x16_bf16(pa, vf, o[db], 0, 0, 0);
      }
    }
    __builtin_amdgcn_s_setprio(0);
  }
  // ---- epilogue ----
  const float linv = 1.0f / lrun;
#pragma unroll
  for (int reg = 0; reg < 16; ++reg) {
    const int r = (reg & 3) + 8 * (reg >> 2) + 4 * hi;
    const float li = __shfl(linv, r, 64);
    const int qr = q0w + r;
#pragma unroll
    for (int db = 0; db < 4; ++db) {
      attn_out[(size_t)(b * 2048 + qr) * 2048 + h * 128 + db * 32 + l31] = f2b(o[db][reg] * li);
    }
  }
}

// ---------------- launch ----------------
extern "C" void kernel_launch(void* const* d_in, const int* in_sizes, int n_in,
                              void* d_out, int out_size, void* d_ws, size_t ws_size,
                              hipStream_t stream) {
  const float* x     = (const float*)d_in[0];
  const float* freqs = (const float*)d_in[1];
  const int*   pos   = (const int*)d_in[2];
  const float* Wqk   = (const float*)d_in[3];
  const float* Wv    = (const float*)d_in[4];
  const float* Wo    = (const float*)d_in[5];
  const float* c1w   = (const float*)d_in[6];
  const float* c1b   = (const float*)d_in[7];
  const float* c2w   = (const float*)d_in[8];
  const float* c2b   = (const float*)d_in[9];
  const float* lnw   = (const float*)d_in[10];
  const float* lf1   = (const float*)d_in[11];
  const float* lf2   = (const float*)d_in[12];
  float* out = (float*)d_out;

  // ---- 128MB arena, explicit aliasing (lifetimes audited) ----
  char* ws = (char*)d_ws;
  const size_t MB = 1024 * 1024;
  bf16_t* wv_bf  = (bf16_t*)(ws + 0 * MB);    // [0,8)   dead after v-GEMM
  bf16_t* w1cat  = (bf16_t*)(ws + 8 * MB);    // [8,16)  dead after y1-GEMM
  bf16_t* wqk_bf = (bf16_t*)(ws + 16 * MB);   // [16,32) dead after qk-GEMM
  bf16_t* wo_bf  = (bf16_t*)(ws + 32 * MB);   // [32,40) until final GEMM
  bf16_t* w2cat  = (bf16_t*)(ws + 40 * MB);   // [40,48) dead after y2-GEMM
  bf16_t* xcat   = (bf16_t*)(ws + 48 * MB);   // [48,80) dead after y1-GEMM
  bf16_t* y1cat  = (bf16_t*)(ws + 80 * MB);   // [80,96) dead after y2-GEMM + tails
  bf16_t* vt_att = (bf16_t*)(ws + 96 * MB);   // [96,112) until attn
  bf16_t* q_att  = (bf16_t*)(ws + 112 * MB);  // [112,128) until attn
  // aliases (after predecessor death):
  float*  y2_f   = (float*)(ws + 48 * MB);    // over xcat [48,80)
  bf16_t* lfo_bf = (bf16_t*)(ws + 80 * MB);   // over y1cat [80,96)
  bf16_t* k_att  = (bf16_t*)(ws + 0 * MB);    // over wv_bf+w1cat [0,16)
  bf16_t* attn_b = (bf16_t*)(ws + 48 * MB);   // over y2_f [48,64)

  // pack weights (merged) + activations
  k_pack_weights<<<2048, 256, 0, stream>>>(Wv, Wqk, Wo, c1w, c2w, wv_bf, wqk_bf, wo_bf,
                                           w1cat, w2cat);
  k_pack_x<<<2048, 256, 0, stream>>>(x, lf1, xcat);
  k_lf2fill<<<8, 256, 0, stream>>>(lf2, y1cat);

  // v = x @ Wv^T, epilogue writes V^T (B,NH,HD,S) directly
  gemm_epi<EPI_VT, 0><<<dim3(Mm / 128, 2048 / 128), 256, 0, stream>>>(
      xcat + 2048, wv_bf, vt_att, nullptr, nullptr, nullptr, nullptr, Mm, 2048, 2048, 4096);
  // y1 = xcat @ w1cat^T + b1, epilogue writes both halves of y1cat (bf16)
  gemm_epi<EPI_Y1CAT, 1><<<dim3(Mm / 128, 1024 / 128), 256, 0, stream>>>(
      xcat, w1cat, y1cat, nullptr, c1b, nullptr, nullptr, Mm, 1024, 4096, 4096);
  // tails (x last row fp32; y1 last row from y1cat)
  k_tails<<<24, 256, 0, stream>>>(x, y1cat, out);
  // y2 = y1cat @ w2cat^T + b2 (fp32, over xcat)
  gemm_epi<EPI_F32, 1><<<dim3(Mm / 128, 2048 / 128), 256, 0, stream>>>(
      y1cat, w2cat, y2_f, nullptr, c2b, nullptr, nullptr, Mm, 2048, 2048, 2048);
  // lf_out = rmsnorm(y2 + x) (over y1cat)
  k_rmsnorm<<<Mm, 256, 0, stream>>>(y2_f, x, lnw, lfo_bf);
  // qk = lf_out @ Wqk^T, epilogue applies RoPE + writes q_att / k_att
  gemm_epi<EPI_ROPE, 0><<<dim3(Mm / 128, 4096 / 128), 256, 0, stream>>>(
      lfo_bf, wqk_bf, q_att, k_att, nullptr, pos, freqs, Mm, 4096, 2048, 2048);
  // attention -> attn_b (over y2_f)
  k_attn3<<<dim3(Bb * NHh, Ss / 128), 256, 0, stream>>>(q_att, k_att, vt_att, attn_b);
  // out = attn @ Wo^T (fp32 to d_out)
  gemm_epi<EPI_F32, 0><<<dim3(Mm / 128, 2048 / 128), 256, 0, stream>>>(
      attn_b, wo_bf, out, nullptr, nullptr, nullptr, nullptr, Mm, 2048, 2048, 2048);
}

// Round 8
// 580.435 us; speedup vs baseline: 1.1104x; 1.1104x over previous
//
#include <hip/hip_runtime.h>
#include <hip/hip_bf16.h>
#include <stdint.h>

// Problem constants
#define Bb 2
#define Ss 2048
#define Hh 2048
#define NHh 16
#define HDd 128
#define Pp 2048
#define Mm 4096   // B*S

typedef __bf16 bf16x8 __attribute__((ext_vector_type(8)));
typedef float f32x4 __attribute__((ext_vector_type(4)));
typedef float f32x16 __attribute__((ext_vector_type(16)));
typedef __hip_bfloat16 bf16_t;

static __device__ __forceinline__ bf16_t f2b(float f) { return __float2bfloat16(f); }
static __device__ __forceinline__ float b2f(bf16_t b) { return __bfloat162float(b); }

// ---------------- merged weight pack kernel ----------------
__global__ void k_pack_weights(const float* __restrict__ Wv, const float* __restrict__ Wqk,
                               const float* __restrict__ Wo, const float* __restrict__ c1w,
                               const float* __restrict__ c2w, bf16_t* __restrict__ wv_bf,
                               bf16_t* __restrict__ wqk_bf, bf16_t* __restrict__ wo_bf,
                               bf16_t* __restrict__ w1cat, bf16_t* __restrict__ w2cat) {
  const int M4 = 4 * 1024 * 1024;
  int stride = gridDim.x * blockDim.x;
  for (int i = blockIdx.x * blockDim.x + threadIdx.x; i < 6 * M4; i += stride) {
    if (i < M4) {
      wv_bf[i] = f2b(Wv[i]);
    } else if (i < 3 * M4) {
      int j = i - M4;
      wqk_bf[j] = f2b(Wqk[j]);
    } else if (i < 4 * M4) {
      int j = i - 3 * M4;
      wo_bf[j] = f2b(Wo[j]);
    } else if (i < 5 * M4) {
      int j = i - 4 * M4;
      int o = j >> 12, hp = j & 4095;
      int t = hp >> 11, h = hp & 2047;
      w1cat[j] = f2b(c1w[((size_t)o * 2048 + h) * 2 + t]);
    } else {
      int j = i - 5 * M4;
      int o = j >> 11, cp = j & 2047;
      int t = cp >> 10, c = cp & 1023;
      w2cat[j] = f2b(c2w[((size_t)o * 1024 + c) * 2 + t]);
    }
  }
}

// x fp32 (B,S,H) -> xcat bf16 (4096,4096) = [x_shift | x]  (float4 vectorized)
__global__ void k_pack_x(const float* __restrict__ x, const float* __restrict__ lf1,
                         bf16_t* __restrict__ xcat) {
  int stride = gridDim.x * blockDim.x;
  const int n4 = Mm * Hh / 4;
  for (int i = blockIdx.x * blockDim.x + threadIdx.x; i < n4; i += stride) {
    int e = i * 4;
    int m = e >> 11, h = e & 2047;
    int b = m >> 11, s = m & 2047;
    float4 xv = *reinterpret_cast<const float4*>(&x[e]);
    bf16_t o4[4];
    o4[0] = f2b(xv.x); o4[1] = f2b(xv.y); o4[2] = f2b(xv.z); o4[3] = f2b(xv.w);
    *reinterpret_cast<uint64_t*>(&xcat[(size_t)m * 4096 + 2048 + h]) =
        *reinterpret_cast<const uint64_t*>(o4);
    float4 xs = (s == 0) ? *reinterpret_cast<const float4*>(&lf1[b * 2048 + h])
                         : *reinterpret_cast<const float4*>(&x[e - 2048]);
    o4[0] = f2b(xs.x); o4[1] = f2b(xs.y); o4[2] = f2b(xs.z); o4[3] = f2b(xs.w);
    *reinterpret_cast<uint64_t*>(&xcat[(size_t)m * 4096 + h]) =
        *reinterpret_cast<const uint64_t*>(o4);
  }
}

// y1cat left-half rows s==0 come from lf2 cache
__global__ void k_lf2fill(const float* __restrict__ lf2, bf16_t* __restrict__ y1cat) {
  int i = blockIdx.x * 256 + threadIdx.x;
  if (i >= 2048) return;
  int b = i >> 10, c = i & 1023;
  y1cat[(size_t)(b * 2048) * 2048 + c] = f2b(lf2[b * 1024 + c]);
}

// lf_out = rmsnorm(y2 + x, ln_w)  -> bf16 (4096,2048)  (float4 vectorized)
__global__ __launch_bounds__(256) void k_rmsnorm(const float* __restrict__ y2,
                                                 const float* __restrict__ x,
                                                 const float* __restrict__ w,
                                                 bf16_t* __restrict__ out) {
  int m = blockIdx.x;
  const float* yr = y2 + (size_t)m * 2048;
  const float* xr = x + (size_t)m * 2048;
  int tid = threadIdx.x;
  const int base = tid * 8;
  float4 ya = *reinterpret_cast<const float4*>(yr + base);
  float4 yb = *reinterpret_cast<const float4*>(yr + base + 4);
  float4 xa = *reinterpret_cast<const float4*>(xr + base);
  float4 xb = *reinterpret_cast<const float4*>(xr + base + 4);
  float t[8] = {ya.x + xa.x, ya.y + xa.y, ya.z + xa.z, ya.w + xa.w,
                yb.x + xb.x, yb.y + xb.y, yb.z + xb.z, yb.w + xb.w};
  float ss = 0.0f;
#pragma unroll
  for (int j = 0; j < 8; ++j) ss += t[j] * t[j];
#pragma unroll
  for (int o = 32; o >= 1; o >>= 1) ss += __shfl_xor(ss, o, 64);
  __shared__ float red[4];
  if ((tid & 63) == 0) red[tid >> 6] = ss;
  __syncthreads();
  float tot = red[0] + red[1] + red[2] + red[3];
  float rs = rsqrtf(tot * (1.0f / 2048.0f) + 1e-6f);
  float4 wa = *reinterpret_cast<const float4*>(w + base);
  float4 wb = *reinterpret_cast<const float4*>(w + base + 4);
  float wv[8] = {wa.x, wa.y, wa.z, wa.w, wb.x, wb.y, wb.z, wb.w};
  bf16_t o8[8];
#pragma unroll
  for (int j = 0; j < 8; ++j) o8[j] = f2b(t[j] * wv[j] * rs);
  *reinterpret_cast<uint4*>(&out[(size_t)m * 2048 + base]) =
      *reinterpret_cast<const uint4*>(o8);
}

// tails: lf1_new = x[:, S-1, :] (fp32), lf2_new = y1[:, S-1, :] (from y1cat bf16)
__global__ void k_tails(const float* __restrict__ x, const bf16_t* __restrict__ y1cat,
                        float* __restrict__ out) {
  int i = blockIdx.x * 256 + threadIdx.x;
  if (i >= 4096 + 2048) return;
  const size_t off = (size_t)Mm * Hh;  // 8388608
  if (i < 4096) {
    int b = i >> 11, h = i & 2047;
    out[off + i] = x[((size_t)b * 2048 + 2047) * 2048 + h];
  } else {
    int j = i - 4096;
    int b = j >> 10, c = j & 1023;
    out[off + 4096 + j] = b2f(y1cat[((size_t)b * 2048 + 2047) * 2048 + 1024 + c]);
  }
}

// ---------------- GEMM: C = A(M,K; lda) @ W(N,K)^T with fused epilogues ----------------
// Double-buffered LDS, 2-phase: issue next-tile global_load_lds BEFORE this tile's
// ds_read+MFMA; single __syncthreads per K-step (drain covers loads that flew under MFMA).
#define EPI_F32 0
#define EPI_Y1CAT 1
#define EPI_ROPE 2
#define EPI_VT 3

template <int EPI, int HAS_BIAS>
__global__ __launch_bounds__(256) void gemm_epi(const bf16_t* __restrict__ A,
                                                const bf16_t* __restrict__ Bw,
                                                void* __restrict__ C1, void* __restrict__ C2,
                                                const float* __restrict__ bias,
                                                const int* __restrict__ posp,
                                                const float* __restrict__ freqs,
                                                int M, int N, int K, int lda) {
  // buf0: A[0,16K) B[16K,32K) ; buf1: A[32K,48K) B[48K,64K). Epilogue tiles overlay.
  __shared__ __align__(16) char smem[65536];

  const int tid = threadIdx.x;
  const int lane = tid & 63;
  const int row0 = blockIdx.x * 128;
  const int col0 = blockIdx.y * 128;
  const int wr = ((tid >> 6) >> 1) * 64;
  const int wc = ((tid >> 6) & 1) * 64;
  const int lr = lane & 15;
  const int lg = lane >> 4;

  f32x4 acc[4][4];
#pragma unroll
  for (int i = 0; i < 4; ++i)
#pragma unroll
    for (int j = 0; j < 4; ++j) acc[i][j] = f32x4{0.f, 0.f, 0.f, 0.f};

  auto stage = [&](int buf, int k0) {
    bf16_t* dA = (bf16_t*)(smem + buf * 32768);
    bf16_t* dB = (bf16_t*)(smem + buf * 32768 + 16384);
#pragma unroll
    for (int is = 0; is < 4; ++is) {
      const int e = is * 2048 + tid * 8;
      const int r = e >> 6, c = e & 63;
      __builtin_amdgcn_global_load_lds(
          (const __attribute__((address_space(1))) void*)(A + (size_t)(row0 + r) * lda + (k0 + c)),
          (__attribute__((address_space(3))) void*)(&dA[e]), 16, 0, 0);
      __builtin_amdgcn_global_load_lds(
          (const __attribute__((address_space(1))) void*)(Bw + (size_t)(col0 + r) * K + (k0 + c)),
          (__attribute__((address_space(3))) void*)(&dB[e]), 16, 0, 0);
    }
  };

  const int nt = K / 64;
  stage(0, 0);
  __syncthreads();  // buf0 ready
  for (int t = 0; t < nt; ++t) {
    const int cur = t & 1;
    if (t + 1 < nt) stage(cur ^ 1, (t + 1) * 64);  // loads fly under this tile's MFMA
    __builtin_amdgcn_sched_barrier(0);             // pin stage-issue above ds_reads
    const bf16_t* sA = (const bf16_t*)(smem + cur * 32768);
    const bf16_t* sB = (const bf16_t*)(smem + cur * 32768 + 16384);
    __builtin_amdgcn_s_setprio(1);
#pragma unroll
    for (int ks = 0; ks < 2; ++ks) {
      bf16x8 af[4], bfg[4];
#pragma unroll
      for (int mi = 0; mi < 4; ++mi)
        af[mi] = *reinterpret_cast<const bf16x8*>(&sA[(wr + mi * 16 + lr) * 64 + ks * 32 + lg * 8]);
#pragma unroll
      for (int ni = 0; ni < 4; ++ni)
        bfg[ni] = *reinterpret_cast<const bf16x8*>(&sB[(wc + ni * 16 + lr) * 64 + ks * 32 + lg * 8]);
#pragma unroll
      for (int mi = 0; mi < 4; ++mi)
#pragma unroll
        for (int ni = 0; ni < 4; ++ni)
          acc[mi][ni] = __builtin_amdgcn_mfma_f32_16x16x32_bf16(af[mi], bfg[ni], acc[mi][ni], 0, 0, 0);
    }
    __builtin_amdgcn_s_setprio(0);
    __syncthreads();  // all waves done reading buf[cur]; next-tile loads drained
  }

  // ---- epilogues. Fragment (mi,ni,r): local row rl=wr+mi*16+lg*4+r, col cl=wc+ni*16+lr ----
  if constexpr (EPI == EPI_F32) {
#pragma unroll
    for (int mi = 0; mi < 4; ++mi)
#pragma unroll
      for (int ni = 0; ni < 4; ++ni) {
        const int cc = col0 + wc + ni * 16 + lr;
        float bv = HAS_BIAS ? bias[cc] : 0.0f;
#pragma unroll
        for (int r = 0; r < 4; ++r) {
          const int rr = row0 + wr + mi * 16 + lg * 4 + r;
          ((float*)C1)[(size_t)rr * N + cc] = acc[mi][ni][r] + bv;
        }
      }
  } else if constexpr (EPI == EPI_Y1CAT) {
    bf16_t* y1cat = (bf16_t*)C1;
#pragma unroll
    for (int mi = 0; mi < 4; ++mi)
#pragma unroll
      for (int ni = 0; ni < 4; ++ni) {
        const int cc = col0 + wc + ni * 16 + lr;  // 0..1023
        float bv = HAS_BIAS ? bias[cc] : 0.0f;
#pragma unroll
        for (int r = 0; r < 4; ++r) {
          const int rr = row0 + wr + mi * 16 + lg * 4 + r;
          bf16_t v = f2b(acc[mi][ni][r] + bv);
          y1cat[(size_t)rr * 2048 + 1024 + cc] = v;
          if ((rr & 2047) != 2047) y1cat[(size_t)(rr + 1) * 2048 + cc] = v;
        }
      }
  } else if constexpr (EPI == EPI_ROPE) {
    // col-block 128 = (head h, q|k half). Tile overlays staging LDS after barrier.
    __syncthreads();
    bf16_t(*tile)[136] = (bf16_t(*)[136])smem;
#pragma unroll
    for (int mi = 0; mi < 4; ++mi)
#pragma unroll
      for (int ni = 0; ni < 4; ++ni) {
        const int cl = wc + ni * 16 + lr;
#pragma unroll
        for (int r = 0; r < 4; ++r) {
          const int rl = wr + mi * 16 + lg * 4 + r;
          tile[rl][cl] = f2b(acc[mi][ni][r]);
        }
      }
    __syncthreads();
    const int r = tid >> 1, half = tid & 1;
    const int m = row0 + r;
    const int s = m & 2047, bb = m >> 11;
    const int cb = col0 >> 7, h = cb >> 1, isk = cb & 1;
    const int pos = posp[m];
    const float* fr = freqs + (size_t)pos * HDd;
    const float qs = isk ? 1.0f : 0.08838834764831845f;
    bf16_t* dst = (bf16_t*)(isk ? C2 : C1) + ((size_t)(bb * NHh + h) * Ss + s) * HDd + half * 64;
#pragma unroll
    for (int j = 0; j < 8; ++j) {
      bf16x8 lo = *reinterpret_cast<const bf16x8*>(&tile[r][j * 8]);
      bf16x8 hv = *reinterpret_cast<const bf16x8*>(&tile[r][64 + j * 8]);
      bf16x8 ov;
#pragma unroll
      for (int e = 0; e < 8; ++e) {
        float f = fr[j * 8 + e];
        float sn, cs;
        __sincosf(f, &sn, &cs);
        float v0 = b2f((bf16_t)lo[e]), v1 = b2f((bf16_t)hv[e]);
        float o = half ? (v1 * cs + v0 * sn) : (v0 * cs - v1 * sn);
        ov[e] = (__bf16)f2b(o * qs);
      }
      *reinterpret_cast<bf16x8*>(dst + j * 8) = ov;
    }
  } else if constexpr (EPI == EPI_VT) {
    // col-block 128 = head h's d range. Transposed tile overlays staging LDS.
    __syncthreads();
    bf16_t(*ttile)[136] = (bf16_t(*)[136])smem;
#pragma unroll
    for (int mi = 0; mi < 4; ++mi)
#pragma unroll
      for (int ni = 0; ni < 4; ++ni) {
        const int cl = wc + ni * 16 + lr;
#pragma unroll
        for (int r = 0; r < 4; ++r) {
          const int rl = wr + mi * 16 + lg * 4 + r;
          ttile[cl][rl] = f2b(acc[mi][ni][r]);
        }
      }
    __syncthreads();
    const int d = tid >> 1, sc = tid & 1;
    const int bb = row0 >> 11, s0 = row0 & 2047, h = col0 >> 7;
    bf16_t* dst = (bf16_t*)C1 + ((size_t)(bb * NHh + h) * HDd + d) * Ss + s0 + sc * 64;
#pragma unroll
    for (int j = 0; j < 8; ++j)
      *reinterpret_cast<bf16x8*>(dst + j * 8) =
          *reinterpret_cast<const bf16x8*>(&ttile[d][sc * 64 + j * 8]);
  }
}

// ---------------- flash attention v3 ----------------
// grid (32, 16). Balanced y-remap: y<8 -> q-tile 15-y (heavy first), y>=8 -> y-8.
__global__ __launch_bounds__(256) void k_attn3(const bf16_t* __restrict__ qa,
                                               const bf16_t* __restrict__ ka,
                                               const bf16_t* __restrict__ vt,
                                               bf16_t* __restrict__ attn_out) {
  __shared__ bf16_t kbuf[64 * 128];
  __shared__ bf16_t vbuf[128 * 64];
  __shared__ bf16_t pbuf[4][32 * 64];

  const int tid = threadIdx.x;
  const int wave = tid >> 6, lane = tid & 63;
  const int l31 = lane & 31, hi = lane >> 5;
  const int bh = blockIdx.x;
  const int yy = blockIdx.y;
  const int jq = (yy < 8) ? (15 - yy) : (yy - 8);
  const int q0b = jq * 128;
  const int q0w = q0b + wave * 32;
  const int b = bh >> 4, h = bh & 15;

  const bf16_t* Q = qa + (size_t)bh * Ss * HDd;
  const bf16_t* K = ka + (size_t)bh * Ss * HDd;
  const bf16_t* V = vt + (size_t)bh * HDd * Ss;
  char* pw = (char*)&pbuf[wave][0];

  bf16x8 qf[8];
#pragma unroll
  for (int dc = 0; dc < 8; ++dc)
    qf[dc] = *reinterpret_cast<const bf16x8*>(&Q[(size_t)(q0w + l31) * HDd + dc * 16 + hi * 8]);

  f32x16 o[4];
#pragma unroll
  for (int db = 0; db < 4; ++db)
#pragma unroll
    for (int i = 0; i < 16; ++i) o[db][i] = 0.f;
  float mrun = -3e38f, lrun = 0.f;
  const int qrow = q0w + l31;

  const int nkt = q0b / 64 + 2;
  bf16x8 pk[4], pv[4];
  auto loadt = [&](int kt) {
    const int k0l = kt * 64;
#pragma unroll
    for (int i = 0; i < 4; ++i) {
      pk[i] = *reinterpret_cast<const bf16x8*>(
          &K[(size_t)(k0l + (tid >> 2)) * HDd + ((tid & 3) + 4 * i) * 8]);
      pv[i] = *reinterpret_cast<const bf16x8*>(
          &V[(size_t)(tid >> 1) * Ss + k0l + ((tid & 1) * 4 + i) * 8]);
    }
  };
  loadt(0);

  for (int kt = 0; kt < nkt; ++kt) {
    const int k0 = kt * 64;
    __syncthreads();
    {
      const int kr = tid >> 2, vr = tid >> 1;
#pragma unroll
      for (int i = 0; i < 4; ++i) {
        const int ku = (tid & 3) + 4 * i;
        *reinterpret_cast<bf16x8*>((char*)kbuf + kr * 256 + ((ku * 16) ^ ((kr & 7) << 4))) = pk[i];
        const int vu = (tid & 1) * 4 + i;
        *reinterpret_cast<bf16x8*>((char*)vbuf + vr * 128 + ((vu * 16) ^ ((vr & 7) << 4))) = pv[i];
      }
    }
    __syncthreads();
    if (kt + 1 < nkt) loadt(kt + 1);  // overlap next-tile loads with compute (T14)
    if (k0 > q0w + 31) continue;

    // ---- QK^T ----
    f32x16 s0, s1;
#pragma unroll
    for (int i = 0; i < 16; ++i) { s0[i] = 0.f; s1[i] = 0.f; }
    __builtin_amdgcn_s_setprio(1);
#pragma unroll
    for (int dc = 0; dc < 8; ++dc) {
      const int off = (dc * 32 + hi * 16) ^ ((l31 & 7) << 4);
      bf16x8 kf0 = *reinterpret_cast<const bf16x8*>((const char*)kbuf + l31 * 256 + off);
      bf16x8 kf1 = *reinterpret_cast<const bf16x8*>((const char*)kbuf + (32 + l31) * 256 + off);
      s0 = __builtin_amdgcn_mfma_f32_32x32x16_bf16(kf0, qf[dc], s0, 0, 0, 0);
      s1 = __builtin_amdgcn_mfma_f32_32x32x16_bf16(kf1, qf[dc], s1, 0, 0, 0);
    }
    __builtin_amdgcn_s_setprio(0);
    // ---- mask ----
    if (k0 + 63 > q0w) {
#pragma unroll
      for (int reg = 0; reg < 16; ++reg) {
        const int key = k0 + (reg & 3) + 8 * (reg >> 2) + 4 * hi;
        if (key > qrow) s0[reg] = -1e30f;
        if (key + 32 > qrow) s1[reg] = -1e30f;
      }
    }
    // ---- online softmax ----
    float pm = fmaxf(s0[0], s1[0]);
#pragma unroll
    for (int reg = 1; reg < 16; ++reg) pm = fmaxf(pm, fmaxf(s0[reg], s1[reg]));
    pm = fmaxf(pm, __shfl_xor(pm, 32, 64));
    if (!__all(pm - mrun <= 8.0f)) {  // defer-max (T13)
      const float mnew = fmaxf(mrun, pm);
      const float alpha = __expf(mrun - mnew);
      lrun *= alpha;
#pragma unroll
      for (int reg = 0; reg < 16; ++reg) {
        const int r = (reg & 3) + 8 * (reg >> 2) + 4 * hi;
        const float ar = __shfl(alpha, r, 64);
        o[0][reg] *= ar; o[1][reg] *= ar; o[2][reg] *= ar; o[3][reg] *= ar;
      }
      mrun = mnew;
    }
    float psum = 0.f;
#pragma unroll
    for (int reg = 0; reg < 16; ++reg) {
      s0[reg] = __expf(s0[reg] - mrun); psum += s0[reg];
      s1[reg] = __expf(s1[reg] - mrun); psum += s1[reg];
    }
    psum += __shfl_xor(psum, 32, 64);
    lrun += psum;
    // ---- P -> bf16 -> per-wave swizzled LDS ----
#pragma unroll
    for (int g = 0; g < 4; ++g) {
      uint32_t w0, w1, w2, w3;
      asm("v_cvt_pk_bf16_f32 %0, %1, %2" : "=v"(w0) : "v"(s0[4 * g]), "v"(s0[4 * g + 1]));
      asm("v_cvt_pk_bf16_f32 %0, %1, %2" : "=v"(w1) : "v"(s0[4 * g + 2]), "v"(s0[4 * g + 3]));
      asm("v_cvt_pk_bf16_f32 %0, %1, %2" : "=v"(w2) : "v"(s1[4 * g]), "v"(s1[4 * g + 1]));
      asm("v_cvt_pk_bf16_f32 %0, %1, %2" : "=v"(w3) : "v"(s1[4 * g + 2]), "v"(s1[4 * g + 3]));
      const int key0 = 8 * g + 4 * hi;
      const int sw = (l31 & 7) << 4;
      *reinterpret_cast<uint2*>(pw + l31 * 128 + ((key0 * 2) ^ sw)) = uint2{w0, w1};
      *reinterpret_cast<uint2*>(pw + l31 * 128 + (((key0 + 32) * 2) ^ sw)) = uint2{w2, w3};
    }
    // ---- PV ----
    __builtin_amdgcn_s_setprio(1);
#pragma unroll
    for (int kc = 0; kc < 4; ++kc) {
      bf16x8 pa = *reinterpret_cast<const bf16x8*>(
          pw + l31 * 128 + ((kc * 32 + hi * 16) ^ ((l31 & 7) << 4)));
#pragma unroll
      for (int db = 0; db < 4; ++db) {
        const int d = db * 32 + l31;
        bf16x8 vf = *reinterpret_cast<const bf16x8*>(
            (const char*)vbuf + d * 128 + ((kc * 32 + hi * 16) ^ ((d & 7) << 4)));
        o[db] = __builtin_amdgcn_mfma_f32_32x32x16_bf16(pa, vf, o[db], 0, 0, 0);
      }
    }
    __builtin_amdgcn_s_setprio(0);
  }
  // ---- epilogue ----
  const float linv = 1.0f / lrun;
#pragma unroll
  for (int reg = 0; reg < 16; ++reg) {
    const int r = (reg & 3) + 8 * (reg >> 2) + 4 * hi;
    const float li = __shfl(linv, r, 64);
    const int qr = q0w + r;
#pragma unroll
    for (int db = 0; db < 4; ++db) {
      attn_out[(size_t)(b * 2048 + qr) * 2048 + h * 128 + db * 32 + l31] = f2b(o[db][reg] * li);
    }
  }
}

// ---------------- launch ----------------
extern "C" void kernel_launch(void* const* d_in, const int* in_sizes, int n_in,
                              void* d_out, int out_size, void* d_ws, size_t ws_size,
                              hipStream_t stream) {
  const float* x     = (const float*)d_in[0];
  const float* freqs = (const float*)d_in[1];
  const int*   pos   = (const int*)d_in[2];
  const float* Wqk   = (const float*)d_in[3];
  const float* Wv    = (const float*)d_in[4];
  const float* Wo    = (const float*)d_in[5];
  const float* c1w   = (const float*)d_in[6];
  const float* c1b   = (const float*)d_in[7];
  const float* c2w   = (const float*)d_in[8];
  const float* c2b   = (const float*)d_in[9];
  const float* lnw   = (const float*)d_in[10];
  const float* lf1   = (const float*)d_in[11];
  const float* lf2   = (const float*)d_in[12];
  float* out = (float*)d_out;

  // ---- 128MB arena, explicit aliasing (lifetimes audited) ----
  char* ws = (char*)d_ws;
  const size_t MB = 1024 * 1024;
  bf16_t* wv_bf  = (bf16_t*)(ws + 0 * MB);    // [0,8)   dead after v-GEMM
  bf16_t* w1cat  = (bf16_t*)(ws + 8 * MB);    // [8,16)  dead after y1-GEMM
  bf16_t* wqk_bf = (bf16_t*)(ws + 16 * MB);   // [16,32) dead after qk-GEMM
  bf16_t* wo_bf  = (bf16_t*)(ws + 32 * MB);   // [32,40) until final GEMM
  bf16_t* w2cat  = (bf16_t*)(ws + 40 * MB);   // [40,48) dead after y2-GEMM
  bf16_t* xcat   = (bf16_t*)(ws + 48 * MB);   // [48,80) dead after y1-GEMM
  bf16_t* y1cat  = (bf16_t*)(ws + 80 * MB);   // [80,96) dead after y2-GEMM + tails
  bf16_t* vt_att = (bf16_t*)(ws + 96 * MB);   // [96,112) until attn
  bf16_t* q_att  = (bf16_t*)(ws + 112 * MB);  // [112,128) until attn
  // aliases (after predecessor death):
  float*  y2_f   = (float*)(ws + 48 * MB);    // over xcat [48,80)
  bf16_t* lfo_bf = (bf16_t*)(ws + 80 * MB);   // over y1cat [80,96)
  bf16_t* k_att  = (bf16_t*)(ws + 0 * MB);    // over wv_bf+w1cat [0,16)
  bf16_t* attn_b = (bf16_t*)(ws + 48 * MB);   // over y2_f [48,64)

  // pack weights (merged) + activations
  k_pack_weights<<<2048, 256, 0, stream>>>(Wv, Wqk, Wo, c1w, c2w, wv_bf, wqk_bf, wo_bf,
                                           w1cat, w2cat);
  k_pack_x<<<2048, 256, 0, stream>>>(x, lf1, xcat);
  k_lf2fill<<<8, 256, 0, stream>>>(lf2, y1cat);

  // v = x @ Wv^T, epilogue writes V^T (B,NH,HD,S) directly
  gemm_epi<EPI_VT, 0><<<dim3(Mm / 128, 2048 / 128), 256, 0, stream>>>(
      xcat + 2048, wv_bf, vt_att, nullptr, nullptr, nullptr, nullptr, Mm, 2048, 2048, 4096);
  // y1 = xcat @ w1cat^T + b1, epilogue writes both halves of y1cat (bf16)
  gemm_epi<EPI_Y1CAT, 1><<<dim3(Mm / 128, 1024 / 128), 256, 0, stream>>>(
      xcat, w1cat, y1cat, nullptr, c1b, nullptr, nullptr, Mm, 1024, 4096, 4096);
  // tails (x last row fp32; y1 last row from y1cat)
  k_tails<<<24, 256, 0, stream>>>(x, y1cat, out);
  // y2 = y1cat @ w2cat^T + b2 (fp32, over xcat)
  gemm_epi<EPI_F32, 1><<<dim3(Mm / 128, 2048 / 128), 256, 0, stream>>>(
      y1cat, w2cat, y2_f, nullptr, c2b, nullptr, nullptr, Mm, 2048, 2048, 2048);
  // lf_out = rmsnorm(y2 + x) (over y1cat)
  k_rmsnorm<<<Mm, 256, 0, stream>>>(y2_f, x, lnw, lfo_bf);
  // qk = lf_out @ Wqk^T, epilogue applies RoPE + writes q_att / k_att
  gemm_epi<EPI_ROPE, 0><<<dim3(Mm / 128, 4096 / 128), 256, 0, stream>>>(
      lfo_bf, wqk_bf, q_att, k_att, nullptr, pos, freqs, Mm, 4096, 2048, 2048);
  // attention -> attn_b (over y2_f)
  k_attn3<<<dim3(Bb * NHh, Ss / 128), 256, 0, stream>>>(q_att, k_att, vt_att, attn_b);
  // out = attn @ Wo^T (fp32 to d_out)
  gemm_epi<EPI_F32, 0><<<dim3(Mm / 128, 2048 / 128), 256, 0, stream>>>(
      attn_b, wo_bf, out, nullptr, nullptr, nullptr, nullptr, Mm, 2048, 2048, 2048);
}